// Round 1
// baseline (7929.285 us; speedup 1.0000x reference)
//
#include <hip/hip_runtime.h>
#include <math.h>

#define NN 10000
#define EE 60000
#define NHEAD 8

__device__ __forceinline__ float gelu_f(float x) {
    return 0.5f * x * (1.0f + erff(x * 0.7071067811865476f));
}

__device__ __forceinline__ void atomicMaxFloat(float* addr, float val) {
    int* ai = (int*)addr;
    int cur = __float_as_int(*addr);
    while (val > __int_as_float(cur)) {
        int prev = atomicCAS(ai, cur, __float_as_int(val));
        if (prev == cur) break;
        cur = prev;
    }
}

// ---------------- generic strided/batched GEMM: C = op(A) @ B + bias ----------
// A: [M,K] row-major with leading dim lda, batch stride Abat (elements)
// B: [K,N] row-major ldb, batch stride Bbat
// C: [M,N] ldc, batch stride Cbat
// K and N must be multiples of 16 / 64 respectively (true for all call sites).
template<bool GELU_A, bool HAS_BIAS>
__global__ __launch_bounds__(256) void gemm_kernel(
    const float* __restrict__ A, int lda, long Abat,
    const float* __restrict__ B, int ldb, long Bbat,
    const float* __restrict__ bias, long bbat,
    float* __restrict__ C, int ldc, long Cbat,
    int M, int N, int K)
{
    __shared__ float As[16][64];
    __shared__ float Bs[16][64];
    const int bz = blockIdx.z;
    A += (long)bz * Abat;
    B += (long)bz * Bbat;
    C += (long)bz * Cbat;
    const float* biasp = HAS_BIAS ? (bias + (long)bz * bbat) : nullptr;

    const int n0 = blockIdx.x * 64;
    const int m0 = blockIdx.y * 64;
    const int t  = threadIdx.x;
    const int tx = t & 15, ty = t >> 4;

    float acc[4][4] = {};

    const int a_m = t >> 2;          // 0..63 (row within A tile)
    const int a_k = (t & 3) << 2;    // 0,4,8,12
    const int b_k = t >> 4;          // 0..15
    const int b_n = (t & 15) << 2;   // 0..60

    for (int k0 = 0; k0 < K; k0 += 16) {
        float4 av = make_float4(0.f, 0.f, 0.f, 0.f);
        const int arow = m0 + a_m;
        if (arow < M)
            av = *(const float4*)(A + (long)arow * lda + (k0 + a_k));
        if (GELU_A) {
            av.x = gelu_f(av.x); av.y = gelu_f(av.y);
            av.z = gelu_f(av.z); av.w = gelu_f(av.w);
        }
        const float4 bv = *(const float4*)(B + (long)(k0 + b_k) * ldb + (n0 + b_n));
        As[a_k + 0][a_m] = av.x;
        As[a_k + 1][a_m] = av.y;
        As[a_k + 2][a_m] = av.z;
        As[a_k + 3][a_m] = av.w;
        *(float4*)&Bs[b_k][b_n] = bv;
        __syncthreads();
        #pragma unroll
        for (int kk = 0; kk < 16; ++kk) {
            float ar[4], br[4];
            *(float4*)ar = *(const float4*)&As[kk][ty << 2];
            *(float4*)br = *(const float4*)&Bs[kk][tx << 2];
            #pragma unroll
            for (int i = 0; i < 4; ++i)
                #pragma unroll
                for (int j = 0; j < 4; ++j)
                    acc[i][j] = fmaf(ar[i], br[j], acc[i][j]);
        }
        __syncthreads();
    }
    #pragma unroll
    for (int i = 0; i < 4; ++i) {
        const int r = m0 + (ty << 2) + i;
        if (r >= M) continue;
        float* cp = C + (long)r * ldc + n0 + (tx << 2);
        #pragma unroll
        for (int j = 0; j < 4; ++j) {
            float v = acc[i][j];
            if (HAS_BIAS) v += biasp[n0 + (tx << 2) + j];
            cp[j] = v;
        }
    }
}

__global__ void fill_kernel(float* __restrict__ p, long n, float v) {
    long i = (long)blockIdx.x * blockDim.x + threadIdx.x;
    if (i < n) p[i] = v;
}

// ---------------- edge kernels (one 64-lane wave per edge) -------------------
__global__ __launch_bounds__(256) void edge_logits_kernel(
    const int* __restrict__ ei, const float* __restrict__ Qd,
    const float* __restrict__ KR, const float* __restrict__ prel,
    float* __restrict__ logit, float* __restrict__ mbuf,
    int HD, int D, float inv_sqrt_d)
{
    const int wave = threadIdx.x >> 6, lane = threadIdx.x & 63;
    const int e = blockIdx.x * 4 + wave;
    if (e >= EE) return;
    const int src = ei[e];
    const int dst = ei[EE + e];
    const float* qrow = Qd + (long)dst * HD;
    const float* krow = KR + (long)src * HD;
    for (int h = 0; h < NHEAD; ++h) {
        float partial = 0.f;
        for (int d = lane; d < D; d += 64)
            partial += qrow[h * D + d] * krow[h * D + d];
        #pragma unroll
        for (int off = 32; off > 0; off >>= 1)
            partial += __shfl_xor(partial, off);
        if (lane == 0) {
            float l = partial * prel[h] * inv_sqrt_d;
            logit[(long)e * NHEAD + h] = l;
            atomicMaxFloat(&mbuf[dst * NHEAD + h], l);
        }
    }
}

__global__ __launch_bounds__(256) void edge_expsum_kernel(
    const int* __restrict__ ei, float* __restrict__ logit,
    const float* __restrict__ mbuf, float* __restrict__ sbuf)
{
    const long tid = (long)blockIdx.x * blockDim.x + threadIdx.x;
    if (tid >= (long)EE * NHEAD) return;
    const int e = (int)(tid >> 3);
    const int h = (int)(tid & 7);
    const int dst = ei[EE + e];
    const float ev = expf(logit[tid] - mbuf[dst * NHEAD + h]);
    logit[tid] = ev;
    atomicAdd(&sbuf[dst * NHEAD + h], ev);
}

__global__ __launch_bounds__(256) void edge_agg_kernel(
    const int* __restrict__ ei, const float* __restrict__ logit,
    const float* __restrict__ sbuf, const float* __restrict__ VR,
    float* __restrict__ outd, int HD, int logD)
{
    const int wave = threadIdx.x >> 6, lane = threadIdx.x & 63;
    const int e = blockIdx.x * 4 + wave;
    if (e >= EE) return;
    const int src = ei[e], dst = ei[EE + e];
    const float* vrow = VR + (long)src * HD;
    float* orow = outd + (long)dst * HD;
    for (int j = lane; j < HD; j += 64) {
        const int h = j >> logD;
        const float w = logit[(long)e * NHEAD + h] / (sbuf[dst * NHEAD + h] + 1e-16f);
        atomicAdd(&orow[j], w * vrow[j]);
    }
}

// ---------------- final: logits = h2 @ Wlin + blin, row softmax --------------
__global__ __launch_bounds__(256) void final_kernel(
    const float* __restrict__ H2, const float* __restrict__ Wlin,
    const float* __restrict__ blin, float* __restrict__ outp)
{
    const int wave = threadIdx.x >> 6, lane = threadIdx.x & 63;
    const int node = blockIdx.x * 4 + wave;
    if (node >= 2 * NN) return;
    const float* hrow = H2 + (long)node * 512;
    float acc[8] = {};
    for (int f = lane; f < 512; f += 64) {
        const float hv = hrow[f];
        const float* wr = Wlin + f * 8;
        #pragma unroll
        for (int o = 0; o < 8; ++o) acc[o] = fmaf(hv, wr[o], acc[o]);
    }
    #pragma unroll
    for (int o = 0; o < 8; ++o)
        #pragma unroll
        for (int off = 32; off > 0; off >>= 1)
            acc[o] += __shfl_xor(acc[o], off);
    if (lane == 0) {
        float mx = -3.0e38f;
        #pragma unroll
        for (int o = 0; o < 8; ++o) { acc[o] += blin[o]; mx = fmaxf(mx, acc[o]); }
        float ssum = 0.f;
        #pragma unroll
        for (int o = 0; o < 8; ++o) { acc[o] = expf(acc[o] - mx); ssum += acc[o]; }
        const float inv = 1.f / ssum;
        #pragma unroll
        for (int o = 0; o < 8; ++o) outp[(long)node * 8 + o] = acc[o] * inv;
    }
}

// =============================== host side ===================================
static void launch_gemm(const float* A, int lda, long Abat,
                        const float* B, int ldb, long Bbat,
                        const float* bias, long bbat,
                        float* C, int ldc, long Cbat,
                        int M, int N, int K, int batch,
                        bool gelu_a, hipStream_t s)
{
    dim3 grid(N / 64, (M + 63) / 64, batch);
    dim3 block(256);
    if (gelu_a) {
        if (bias) gemm_kernel<true, true><<<grid, block, 0, s>>>(A, lda, Abat, B, ldb, Bbat, bias, bbat, C, ldc, Cbat, M, N, K);
        else      gemm_kernel<true, false><<<grid, block, 0, s>>>(A, lda, Abat, B, ldb, Bbat, nullptr, 0, C, ldc, Cbat, M, N, K);
    } else {
        if (bias) gemm_kernel<false, true><<<grid, block, 0, s>>>(A, lda, Abat, B, ldb, Bbat, bias, bbat, C, ldc, Cbat, M, N, K);
        else      gemm_kernel<false, false><<<grid, block, 0, s>>>(A, lda, Abat, B, ldb, Bbat, nullptr, 0, C, ldc, Cbat, M, N, K);
    }
}

static void fill_async(float* p, long n, float v, hipStream_t s) {
    fill_kernel<<<(unsigned)((n + 255) / 256), 256, 0, s>>>(p, n, v);
}

static void run_hgt_layer(
    const float* x, int Fin, int Fout,
    const float* Wk, const float* bk,
    const float* Wq, const float* bq,
    const float* Wv, const float* bv,
    const float* Wa, const float* ba,
    const float* arel, const float* mrel, const float* prel,
    const int* const* ei,
    float* Kb, float* Qb, float* Vb, float* KRb, float* VRb,
    float* alpha, float* mbuf, float* sbuf, float* outb, float* hout,
    hipStream_t stream)
{
    const int D = Fout / NHEAD;
    const int logD = (D == 128) ? 7 : 6;
    const float inv_sqrt_d = 1.0f / sqrtf((float)D);
    const long NF_in  = (long)NN * Fin;
    const long NF_out = (long)NN * Fout;

    // K/Q/V projections, batched over T=2 node types
    launch_gemm(x, Fin, NF_in, Wk, Fout, (long)Fin * Fout, bk, Fout, Kb, Fout, NF_out, NN, Fout, Fin, 2, false, stream);
    launch_gemm(x, Fin, NF_in, Wq, Fout, (long)Fin * Fout, bq, Fout, Qb, Fout, NF_out, NN, Fout, Fin, 2, false, stream);
    launch_gemm(x, Fin, NF_in, Wv, Fout, (long)Fin * Fout, bv, Fout, Vb, Fout, NF_out, NN, Fout, Fin, 2, false, stream);

    fill_async(outb, 2 * NF_out, 0.f, stream);

    static const int ST[4] = {0, 0, 1, 1};
    static const int DT[4] = {0, 1, 0, 1};
    for (int e = 0; e < 4; ++e) {
        // per-head relation transforms: KR = K[st] @ a_rel[e], VR = V[st] @ m_rel[e]
        launch_gemm(Kb + (long)ST[e] * NF_out, Fout, D,
                    arel + (long)e * NHEAD * D * D, D, (long)D * D,
                    nullptr, 0, KRb, Fout, D, NN, D, D, NHEAD, false, stream);
        launch_gemm(Vb + (long)ST[e] * NF_out, Fout, D,
                    mrel + (long)e * NHEAD * D * D, D, (long)D * D,
                    nullptr, 0, VRb, Fout, D, NN, D, D, NHEAD, false, stream);
        fill_async(mbuf, (long)NN * NHEAD, -3.0e38f, stream);
        fill_async(sbuf, (long)NN * NHEAD, 0.f, stream);
        edge_logits_kernel<<<EE / 4, 256, 0, stream>>>(
            ei[e], Qb + (long)DT[e] * NF_out, KRb, prel + e * NHEAD,
            alpha, mbuf, Fout, D, inv_sqrt_d);
        edge_expsum_kernel<<<(EE * NHEAD) / 256, 256, 0, stream>>>(ei[e], alpha, mbuf, sbuf);
        edge_agg_kernel<<<EE / 4, 256, 0, stream>>>(
            ei[e], alpha, sbuf, VRb, outb + (long)DT[e] * NF_out, Fout, logD);
    }

    // h = gelu(out) @ Wa + ba
    launch_gemm(outb, Fout, NF_out, Wa, Fout, (long)Fout * Fout, ba, Fout,
                hout, Fout, NF_out, NN, Fout, Fout, 2, true, stream);
}

extern "C" void kernel_launch(void* const* d_in, const int* in_sizes, int n_in,
                              void* d_out, int out_size, void* d_ws, size_t ws_size,
                              hipStream_t stream)
{
    const float* x     = (const float*)d_in[0];
    const int* ei_arr[4] = {(const int*)d_in[1], (const int*)d_in[2],
                            (const int*)d_in[3], (const int*)d_in[4]};
    const float* Wk1 = (const float*)d_in[5];   const float* bk1 = (const float*)d_in[6];
    const float* Wq1 = (const float*)d_in[7];   const float* bq1 = (const float*)d_in[8];
    const float* Wv1 = (const float*)d_in[9];   const float* bv1 = (const float*)d_in[10];
    const float* Wa1 = (const float*)d_in[11];  const float* ba1 = (const float*)d_in[12];
    const float* ar1 = (const float*)d_in[13];  const float* mr1 = (const float*)d_in[14];
    const float* pr1 = (const float*)d_in[15];
    const float* Wk2 = (const float*)d_in[16];  const float* bk2 = (const float*)d_in[17];
    const float* Wq2 = (const float*)d_in[18];  const float* bq2 = (const float*)d_in[19];
    const float* Wv2 = (const float*)d_in[20];  const float* bv2 = (const float*)d_in[21];
    const float* Wa2 = (const float*)d_in[22];  const float* ba2 = (const float*)d_in[23];
    const float* ar2 = (const float*)d_in[24];  const float* mr2 = (const float*)d_in[25];
    const float* pr2 = (const float*)d_in[26];
    const float* Wlin = (const float*)d_in[27]; const float* blin = (const float*)d_in[28];

    // ---- workspace arena (floats); total ≈ 536 MB ----
    float* w = (float*)d_ws;
    size_t off = 0;
    auto take = [&](size_t n) { float* p = w + off; off += n; return p; };
    float* Kb    = take((size_t)2 * NN * 1024);
    float* Qb    = take((size_t)2 * NN * 1024);
    float* Vb    = take((size_t)2 * NN * 1024);
    float* KRb   = take((size_t)NN * 1024);
    float* VRb   = take((size_t)NN * 1024);
    float* alpha = take((size_t)EE * NHEAD);
    float* mbuf  = take((size_t)NN * NHEAD);
    float* sbuf  = take((size_t)NN * NHEAD);
    float* outb  = take((size_t)2 * NN * 1024);
    float* h1    = take((size_t)2 * NN * 1024);
    float* h2    = take((size_t)2 * NN * 512);
    (void)ws_size; (void)in_sizes; (void)n_in; (void)out_size;

    // Layer 1: 2048 -> 1024 (D=128)
    run_hgt_layer(x, 2048, 1024, Wk1, bk1, Wq1, bq1, Wv1, bv1, Wa1, ba1,
                  ar1, mr1, pr1, ei_arr,
                  Kb, Qb, Vb, KRb, VRb, alpha, mbuf, sbuf, outb, h1, stream);
    // Layer 2: 1024 -> 512 (D=64), reuses layer-1 buffers
    run_hgt_layer(h1, 1024, 512, Wk2, bk2, Wq2, bq2, Wv2, bv2, Wa2, ba2,
                  ar2, mr2, pr2, ei_arr,
                  Kb, Qb, Vb, KRb, VRb, alpha, mbuf, sbuf, outb, h2, stream);
    // Final linear + softmax
    final_kernel<<<(2 * NN) / 4, 256, 0, stream>>>(h2, Wlin, blin, (float*)d_out);
}

// Round 2
// 3287.331 us; speedup vs baseline: 2.4121x; 2.4121x over previous
//
#include <hip/hip_runtime.h>
#include <math.h>

#define NN   10000
#define EE   60000
#define NHEAD 8
#define MPAD 10112   // 79 * 128

typedef unsigned short ushort_t;
typedef short bf16x8 __attribute__((ext_vector_type(8)));
typedef float floatx4 __attribute__((ext_vector_type(4)));

__device__ __forceinline__ float gelu_f(float x) {
    return 0.5f * x * (1.0f + erff(x * 0.7071067811865476f));
}
__device__ __forceinline__ float bf2f(ushort_t u) {
    union { unsigned i; float f; } v; v.i = ((unsigned)u) << 16; return v.f;
}
__device__ __forceinline__ ushort_t f2bf(float x) {  // RNE
    unsigned u = __float_as_uint(x);
    u += 0x7fffu + ((u >> 16) & 1u);
    return (ushort_t)(u >> 16);
}
__device__ __forceinline__ void atomicMaxFloat(float* addr, float val) {
    int* ai = (int*)addr;
    int cur = __float_as_int(*addr);
    while (val > __int_as_float(cur)) {
        int prev = atomicCAS(ai, cur, __float_as_int(val));
        if (prev == cur) break;
        cur = prev;
    }
}
__device__ __forceinline__ void gl_lds16(const void* g, const void* l) {
    __builtin_amdgcn_global_load_lds(
        (const __attribute__((address_space(1))) unsigned int*)(unsigned long long)g,
        (__attribute__((address_space(3))) unsigned int*)(unsigned long long)l,
        16, 0, 0);
}

// ============ bf16 MFMA GEMM: C[MPAD x N] = A[MPAD x K] * Bt[N x K]^T + bias =
// A row-major lda (bf16, rows padded to MPAD), Bt row-major [Npad x K] (=B^T),
// C bf16 row-major ldc. K % 32 == 0. Block tile 128x128, BK=32.
__global__ __launch_bounds__(256) void mfma_gemm(
    const ushort_t* __restrict__ A, long Abat, int lda,
    const ushort_t* __restrict__ Bt, long Bbat,
    const float* __restrict__ bias, long bbat,
    ushort_t* __restrict__ C, long Cbat, int ldc,
    int N, int K)
{
    __shared__ __align__(16) ushort_t As[128 * 32];
    __shared__ __align__(16) ushort_t Bs[128 * 32];
    const int t = threadIdx.x, lane = t & 63, w = t >> 6;
    const int quad = lane >> 4, l15 = lane & 15;
    const int m0 = blockIdx.y * 128, n0 = blockIdx.x * 128;
    const int bz = blockIdx.z;
    const ushort_t* Ag = A + (long)bz * Abat + (long)m0 * lda;
    const ushort_t* Bg = Bt + (long)bz * Bbat + (long)n0 * K;
    C += (long)bz * Cbat;
    const float* bp = bias ? bias + (long)bz * bbat : nullptr;

    floatx4 acc[4][4];
    #pragma unroll
    for (int i = 0; i < 4; ++i)
        #pragma unroll
        for (int j = 0; j < 4; ++j)
            acc[i][j] = (floatx4){0.f, 0.f, 0.f, 0.f};

    const int wm = (w >> 1) * 64, wn = (w & 1) * 64;
    // staging chunk geometry: tile = 128 rows x 32 cols bf16 = 512 x 16B chunks
    const int ar0 = t >> 2,         ak0 = (t & 3) * 8;          // chunks 0..255
    const int ar1 = (256 + t) >> 2, ak1 = (t & 3) * 8;          // chunks 256..511
    const char* lA0 = (const char*)As + (size_t)(w * 64) * 16;        // wave-uniform
    const char* lA1 = (const char*)As + (size_t)(256 + w * 64) * 16;
    const char* lB0 = (const char*)Bs + (size_t)(w * 64) * 16;
    const char* lB1 = (const char*)Bs + (size_t)(256 + w * 64) * 16;

    for (int k0 = 0; k0 < K; k0 += 32) {
        gl_lds16(Ag + (long)ar0 * lda + k0 + ak0, lA0);
        gl_lds16(Ag + (long)ar1 * lda + k0 + ak1, lA1);
        gl_lds16(Bg + (long)ar0 * K + k0 + ak0, lB0);
        gl_lds16(Bg + (long)ar1 * K + k0 + ak1, lB1);
        __syncthreads();   // compiler drains vmcnt(0) before s_barrier
        bf16x8 a[4], b[4];
        #pragma unroll
        for (int mi = 0; mi < 4; ++mi)
            a[mi] = *(const bf16x8*)(As + (size_t)(wm + mi * 16 + l15) * 32 + quad * 8);
        #pragma unroll
        for (int ni = 0; ni < 4; ++ni)
            b[ni] = *(const bf16x8*)(Bs + (size_t)(wn + ni * 16 + l15) * 32 + quad * 8);
        #pragma unroll
        for (int mi = 0; mi < 4; ++mi)
            #pragma unroll
            for (int ni = 0; ni < 4; ++ni)
                acc[mi][ni] = __builtin_amdgcn_mfma_f32_16x16x32_bf16(
                    a[mi], b[ni], acc[mi][ni], 0, 0, 0);
        __syncthreads();
    }

    #pragma unroll
    for (int ni = 0; ni < 4; ++ni) {
        const int col = n0 + wn + ni * 16 + l15;
        if (col >= N) continue;
        const float bv = bp ? bp[col] : 0.f;
        #pragma unroll
        for (int mi = 0; mi < 4; ++mi) {
            const int row = m0 + wm + mi * 16 + quad * 4;
            #pragma unroll
            for (int r = 0; r < 4; ++r)
                C[(long)(row + r) * ldc + col] = f2bf(acc[mi][ni][r] + bv);
        }
    }
}

// ============ transpose + fp32->bf16 convert: out[Cpad x R] = in[R x C]^T ====
__global__ void transpose_conv_kernel(
    const float* __restrict__ in, long ibat, int R, int C,
    ushort_t* __restrict__ out, long obat, int Cpad)
{
    __shared__ float tile[32][33];
    in  += (long)blockIdx.z * ibat;
    out += (long)blockIdx.z * obat;
    const int r0 = blockIdx.x * 32, c0 = blockIdx.y * 32;
    const int tx = threadIdx.x, ty = threadIdx.y;
    #pragma unroll
    for (int i = 0; i < 4; ++i) {
        const int r = r0 + ty + i * 8, c = c0 + tx;
        tile[ty + i * 8][tx] = (r < R && c < C) ? in[(long)r * C + c] : 0.f;
    }
    __syncthreads();
    #pragma unroll
    for (int i = 0; i < 4; ++i) {
        const int oc = c0 + ty + i * 8, orr = r0 + tx;
        if (oc < Cpad && orr < R) out[(long)oc * R + orr] = f2bf(tile[tx][ty + i * 8]);
    }
}

// ============ pad-convert (optionally GELU): in fp32 [2][NN][F] -> bf16 [2][MPAD][F]
template<bool GELU>
__global__ void convpad_kernel(const float* __restrict__ in, ushort_t* __restrict__ out, int logF)
{
    const long per = (long)MPAD << logF;
    const long idx = (long)blockIdx.x * 256 + threadIdx.x;
    if (idx >= per) return;
    const int n = (int)(idx >> logF);
    const int c = (int)(idx & ((1 << logF) - 1));
    const int tt = blockIdx.y;
    float v = 0.f;
    if (n < NN) {
        v = in[(((long)tt * NN + n) << logF) + c];
        if (GELU) v = gelu_f(v);
    }
    out[(long)tt * per + idx] = f2bf(v);
}

__global__ void fill_kernel(float* __restrict__ p, long n, float v) {
    long i = (long)blockIdx.x * blockDim.x + threadIdx.x;
    if (i < n) p[i] = v;
}

// ============ edge kernels (one wave per edge), bf16 tables ==================
__global__ __launch_bounds__(256) void edge_logits_kernel(
    const int* __restrict__ ei, const ushort_t* __restrict__ Qd,
    const ushort_t* __restrict__ KR, const float* __restrict__ prel,
    float* __restrict__ logit, float* __restrict__ mbuf,
    int HD, int D, float inv_sqrt_d)
{
    const int wave = threadIdx.x >> 6, lane = threadIdx.x & 63;
    const int e = blockIdx.x * 4 + wave;
    if (e >= EE) return;
    const int src = ei[e];
    const int dst = ei[EE + e];
    const ushort2* q2 = (const ushort2*)(Qd + (long)dst * HD);
    const ushort2* k2 = (const ushort2*)(KR + (long)src * HD);
    const int D2 = D >> 1;
    for (int h = 0; h < NHEAD; ++h) {
        float partial = 0.f;
        for (int j = lane; j < D2; j += 64) {
            const ushort2 qa = q2[h * D2 + j];
            const ushort2 ka = k2[h * D2 + j];
            partial += bf2f(qa.x) * bf2f(ka.x) + bf2f(qa.y) * bf2f(ka.y);
        }
        #pragma unroll
        for (int off = 32; off > 0; off >>= 1)
            partial += __shfl_xor(partial, off);
        if (lane == 0) {
            float l = partial * prel[h] * inv_sqrt_d;
            logit[(long)e * NHEAD + h] = l;
            atomicMaxFloat(&mbuf[dst * NHEAD + h], l);
        }
    }
}

__global__ __launch_bounds__(256) void edge_expsum_kernel(
    const int* __restrict__ ei, float* __restrict__ logit,
    const float* __restrict__ mbuf, float* __restrict__ sbuf)
{
    const long tid = (long)blockIdx.x * blockDim.x + threadIdx.x;
    if (tid >= (long)EE * NHEAD) return;
    const int e = (int)(tid >> 3);
    const int h = (int)(tid & 7);
    const int dst = ei[EE + e];
    const float ev = expf(logit[tid] - mbuf[dst * NHEAD + h]);
    logit[tid] = ev;
    atomicAdd(&sbuf[dst * NHEAD + h], ev);
}

__global__ __launch_bounds__(256) void edge_agg_kernel(
    const int* __restrict__ ei, const float* __restrict__ logit,
    const float* __restrict__ sbuf, const ushort_t* __restrict__ VR,
    float* __restrict__ outd, int HD, int logD)
{
    const int wave = threadIdx.x >> 6, lane = threadIdx.x & 63;
    const int e = blockIdx.x * 4 + wave;
    if (e >= EE) return;
    const int src = ei[e], dst = ei[EE + e];
    const ushort_t* vrow = VR + (long)src * HD;
    float* orow = outd + (long)dst * HD;
    for (int j = lane; j < HD; j += 64) {
        const int h = j >> logD;
        const float wgt = logit[(long)e * NHEAD + h] / (sbuf[dst * NHEAD + h] + 1e-16f);
        atomicAdd(&orow[j], wgt * bf2f(vrow[j]));
    }
}

// ============ final: logits = h2 @ Wlin + blin, row softmax ==================
__global__ __launch_bounds__(256) void final_kernel(
    const ushort_t* __restrict__ H2, const float* __restrict__ Wlin,
    const float* __restrict__ blin, float* __restrict__ outp)
{
    const int wave = threadIdx.x >> 6, lane = threadIdx.x & 63;
    const int node = blockIdx.x * 4 + wave;
    if (node >= 2 * NN) return;
    const int tt = (node >= NN) ? 1 : 0;
    const int n = node - tt * NN;
    const ushort_t* hrow = H2 + ((long)tt * MPAD + n) * 512;
    float acc[8] = {};
    for (int f = lane; f < 512; f += 64) {
        const float hv = bf2f(hrow[f]);
        const float* wr = Wlin + f * 8;
        #pragma unroll
        for (int o = 0; o < 8; ++o) acc[o] = fmaf(hv, wr[o], acc[o]);
    }
    #pragma unroll
    for (int o = 0; o < 8; ++o)
        #pragma unroll
        for (int off = 32; off > 0; off >>= 1)
            acc[o] += __shfl_xor(acc[o], off);
    if (lane == 0) {
        float mx = -3.0e38f;
        #pragma unroll
        for (int o = 0; o < 8; ++o) { acc[o] += blin[o]; mx = fmaxf(mx, acc[o]); }
        float ssum = 0.f;
        #pragma unroll
        for (int o = 0; o < 8; ++o) { acc[o] = expf(acc[o] - mx); ssum += acc[o]; }
        const float inv = 1.f / ssum;
        #pragma unroll
        for (int o = 0; o < 8; ++o) outp[(long)node * 8 + o] = acc[o] * inv;
    }
}

// =============================== host side ===================================
static void gemm_launch(const ushort_t* A, long Abat, int lda,
                        const ushort_t* Bt, long Bbat,
                        const float* bias, long bbat,
                        ushort_t* C, long Cbat, int ldc,
                        int N, int K, int batch, hipStream_t s)
{
    dim3 grid((N + 127) / 128, MPAD / 128, batch);
    mfma_gemm<<<grid, 256, 0, s>>>(A, Abat, lda, Bt, Bbat, bias, bbat, C, Cbat, ldc, N, K);
}

static void tconv_launch(const float* in, long ibat, int R, int C,
                         ushort_t* out, long obat, int Cpad, int batch, hipStream_t s)
{
    dim3 grid((R + 31) / 32, (Cpad + 31) / 32, batch);
    transpose_conv_kernel<<<grid, dim3(32, 8), 0, s>>>(in, ibat, R, C, out, obat, Cpad);
}

static void fill_async(float* p, long n, float v, hipStream_t s) {
    fill_kernel<<<(unsigned)((n + 255) / 256), 256, 0, s>>>(p, n, v);
}

struct LayerBufs {
    ushort_t *Kb, *Qb, *Vb, *KRb, *VRb, *outg;
    float *outb, *alpha, *mbuf, *sbuf;
};

static void run_hgt_layer(
    const ushort_t* xb, int Fin, int Fout,
    const ushort_t* Wkt, const float* bk,
    const ushort_t* Wqt, const float* bq,
    const ushort_t* Wvt, const float* bv,
    const ushort_t* Wat, const float* ba,
    const ushort_t* arelT, const ushort_t* mrelT, const float* prel,
    const int* const* ei, const LayerBufs& B, ushort_t* hout,
    hipStream_t stream)
{
    const int D = Fout / NHEAD;
    const int logD = (D == 128) ? 7 : 6;
    const int logF = (Fout == 1024) ? 10 : 9;
    const float inv_sqrt_d = 1.0f / sqrtf((float)D);
    const long NF = (long)MPAD * Fout;
    const long relB = (long)128 * D;              // Bt batch stride per head (Npad=128)

    // projections
    gemm_launch(xb, (long)MPAD * Fin, Fin, Wkt, (long)Fout * Fin, bk, Fout, B.Kb, NF, Fout, Fout, Fin, 2, stream);
    gemm_launch(xb, (long)MPAD * Fin, Fin, Wqt, (long)Fout * Fin, bq, Fout, B.Qb, NF, Fout, Fout, Fin, 2, stream);
    gemm_launch(xb, (long)MPAD * Fin, Fin, Wvt, (long)Fout * Fin, bv, Fout, B.Vb, NF, Fout, Fout, Fin, 2, stream);

    fill_async(B.outb, (long)2 * NN * Fout, 0.f, stream);

    static const int ST[4] = {0, 0, 1, 1};
    static const int DT[4] = {0, 1, 0, 1};
    for (int e = 0; e < 4; ++e) {
        gemm_launch(B.Kb + (long)ST[e] * NF, D, Fout,
                    arelT + (long)e * NHEAD * relB, relB, nullptr, 0,
                    B.KRb, D, Fout, D, D, NHEAD, stream);
        gemm_launch(B.Vb + (long)ST[e] * NF, D, Fout,
                    mrelT + (long)e * NHEAD * relB, relB, nullptr, 0,
                    B.VRb, D, Fout, D, D, NHEAD, stream);
        fill_async(B.mbuf, (long)NN * NHEAD, -3.0e38f, stream);
        fill_async(B.sbuf, (long)NN * NHEAD, 0.f, stream);
        edge_logits_kernel<<<EE / 4, 256, 0, stream>>>(
            ei[e], B.Qb + (long)DT[e] * NF, B.KRb, prel + e * NHEAD,
            B.alpha, B.mbuf, Fout, D, inv_sqrt_d);
        edge_expsum_kernel<<<(EE * NHEAD) / 256, 256, 0, stream>>>(ei[e], B.alpha, B.mbuf, B.sbuf);
        edge_agg_kernel<<<EE / 4, 256, 0, stream>>>(
            ei[e], B.alpha, B.sbuf, B.VRb, B.outb + (long)DT[e] * NN * Fout, Fout, logD);
    }

    // gelu + convert to bf16 padded, then h = outg @ Wat^T + ba
    {
        const long per = (long)MPAD << logF;
        dim3 grid((unsigned)((per + 255) / 256), 2);
        convpad_kernel<true><<<grid, 256, 0, stream>>>(B.outb, B.outg, logF);
    }
    gemm_launch(B.outg, NF, Fout, Wat, (long)Fout * Fout, ba, Fout, hout, NF, Fout, Fout, Fout, 2, stream);
}

extern "C" void kernel_launch(void* const* d_in, const int* in_sizes, int n_in,
                              void* d_out, int out_size, void* d_ws, size_t ws_size,
                              hipStream_t stream)
{
    const float* x     = (const float*)d_in[0];
    const int* ei_arr[4] = {(const int*)d_in[1], (const int*)d_in[2],
                            (const int*)d_in[3], (const int*)d_in[4]};
    const float* Wk1 = (const float*)d_in[5];   const float* bk1 = (const float*)d_in[6];
    const float* Wq1 = (const float*)d_in[7];   const float* bq1 = (const float*)d_in[8];
    const float* Wv1 = (const float*)d_in[9];   const float* bv1 = (const float*)d_in[10];
    const float* Wa1 = (const float*)d_in[11];  const float* ba1 = (const float*)d_in[12];
    const float* ar1 = (const float*)d_in[13];  const float* mr1 = (const float*)d_in[14];
    const float* pr1 = (const float*)d_in[15];
    const float* Wk2 = (const float*)d_in[16];  const float* bk2 = (const float*)d_in[17];
    const float* Wq2 = (const float*)d_in[18];  const float* bq2 = (const float*)d_in[19];
    const float* Wv2 = (const float*)d_in[20];  const float* bv2 = (const float*)d_in[21];
    const float* Wa2 = (const float*)d_in[22];  const float* ba2 = (const float*)d_in[23];
    const float* ar2 = (const float*)d_in[24];  const float* mr2 = (const float*)d_in[25];
    const float* pr2 = (const float*)d_in[26];
    const float* Wlin = (const float*)d_in[27]; const float* blin = (const float*)d_in[28];
    (void)in_sizes; (void)n_in; (void)out_size; (void)ws_size;

    // ---- workspace arena ----
    char* base = (char*)d_ws;
    size_t off = 0;
    auto takeF = [&](size_t n) { float* p = (float*)(base + off); off += n * 4; return p; };
    auto takeU = [&](size_t n) { ushort_t* p = (ushort_t*)(base + off);
                                 off += n * 2; off = (off + 15) & ~(size_t)15; return p; };

    float* outb  = takeF((size_t)2 * NN * 1024);
    float* alpha = takeF((size_t)EE * NHEAD);
    float* mbuf  = takeF((size_t)NN * NHEAD);
    float* sbuf  = takeF((size_t)NN * NHEAD);

    ushort_t* xb   = takeU((size_t)2 * MPAD * 2048);
    ushort_t* wkt1 = takeU((size_t)2 * 1024 * 2048);
    ushort_t* wqt1 = takeU((size_t)2 * 1024 * 2048);
    ushort_t* wvt1 = takeU((size_t)2 * 1024 * 2048);
    ushort_t* wat1 = takeU((size_t)2 * 1024 * 1024);
    ushort_t* wkt2 = takeU((size_t)2 * 512 * 1024);
    ushort_t* wqt2 = takeU((size_t)2 * 512 * 1024);
    ushort_t* wvt2 = takeU((size_t)2 * 512 * 1024);
    ushort_t* wat2 = takeU((size_t)2 * 512 * 512);
    ushort_t* ar1t = takeU((size_t)32 * 128 * 128);
    ushort_t* mr1t = takeU((size_t)32 * 128 * 128);
    ushort_t* ar2t = takeU((size_t)32 * 128 * 64);
    ushort_t* mr2t = takeU((size_t)32 * 128 * 64);
    ushort_t* Kb   = takeU((size_t)2 * MPAD * 1024);
    ushort_t* Qb   = takeU((size_t)2 * MPAD * 1024);
    ushort_t* Vb   = takeU((size_t)2 * MPAD * 1024);
    ushort_t* KRb  = takeU((size_t)MPAD * 1024);
    ushort_t* VRb  = takeU((size_t)MPAD * 1024);
    ushort_t* outg = takeU((size_t)2 * MPAD * 1024);
    ushort_t* h1b  = takeU((size_t)2 * MPAD * 1024);
    ushort_t* h2b  = takeU((size_t)2 * MPAD * 512);

    // ---- input conversions ----
    {   // x -> bf16 padded
        const long per = (long)MPAD << 11;
        dim3 grid((unsigned)((per + 255) / 256), 2);
        convpad_kernel<false><<<grid, 256, 0, stream>>>(x, xb, 11);
    }
    tconv_launch(Wk1, (long)2048 * 1024, 2048, 1024, wkt1, (long)1024 * 2048, 1024, 2, stream);
    tconv_launch(Wq1, (long)2048 * 1024, 2048, 1024, wqt1, (long)1024 * 2048, 1024, 2, stream);
    tconv_launch(Wv1, (long)2048 * 1024, 2048, 1024, wvt1, (long)1024 * 2048, 1024, 2, stream);
    tconv_launch(Wa1, (long)1024 * 1024, 1024, 1024, wat1, (long)1024 * 1024, 1024, 2, stream);
    tconv_launch(Wk2, (long)1024 * 512, 1024, 512, wkt2, (long)512 * 1024, 512, 2, stream);
    tconv_launch(Wq2, (long)1024 * 512, 1024, 512, wqt2, (long)512 * 1024, 512, 2, stream);
    tconv_launch(Wv2, (long)1024 * 512, 1024, 512, wvt2, (long)512 * 1024, 512, 2, stream);
    tconv_launch(Wa2, (long)512 * 512, 512, 512, wat2, (long)512 * 512, 512, 2, stream);
    tconv_launch(ar1, (long)128 * 128, 128, 128, ar1t, (long)128 * 128, 128, 32, stream);
    tconv_launch(mr1, (long)128 * 128, 128, 128, mr1t, (long)128 * 128, 128, 32, stream);
    tconv_launch(ar2, (long)64 * 64, 64, 64, ar2t, (long)128 * 64, 128, 32, stream);
    tconv_launch(mr2, (long)64 * 64, 64, 64, mr2t, (long)128 * 64, 128, 32, stream);

    LayerBufs B{Kb, Qb, Vb, KRb, VRb, outg, outb, alpha, mbuf, sbuf};

    // Layer 1: 2048 -> 1024 (D=128)
    run_hgt_layer(xb, 2048, 1024, wkt1, bk1, wqt1, bq1, wvt1, bv1, wat1, ba1,
                  ar1t, mr1t, pr1, ei_arr, B, h1b, stream);
    // Layer 2: 1024 -> 512 (D=64)
    run_hgt_layer(h1b, 1024, 512, wkt2, bk2, wqt2, bq2, wvt2, bv2, wat2, ba2,
                  ar2t, mr2t, pr2, ei_arr, B, h2b, stream);

    final_kernel<<<(2 * NN) / 4, 256, 0, stream>>>(h2b, Wlin, blin, (float*)d_out);
}

// Round 3
// 1668.865 us; speedup vs baseline: 4.7513x; 1.9698x over previous
//
#include <hip/hip_runtime.h>
#include <math.h>

#define NN   10000
#define EE   60000
#define NHEAD 8
#define MPAD 10112   // 79 * 128

typedef unsigned short ushort_t;
typedef short bf16x8 __attribute__((ext_vector_type(8)));
typedef unsigned short u16x8 __attribute__((ext_vector_type(8)));
typedef unsigned short u16x4 __attribute__((ext_vector_type(4)));
typedef unsigned short u16x2 __attribute__((ext_vector_type(2)));
typedef float floatx4 __attribute__((ext_vector_type(4)));

__device__ __forceinline__ float gelu_f(float x) {
    return 0.5f * x * (1.0f + erff(x * 0.7071067811865476f));
}
__device__ __forceinline__ float bf2f(ushort_t u) {
    union { unsigned i; float f; } v; v.i = ((unsigned)u) << 16; return v.f;
}
__device__ __forceinline__ ushort_t f2bf(float x) {  // RNE
    unsigned u = __float_as_uint(x);
    u += 0x7fffu + ((u >> 16) & 1u);
    return (ushort_t)(u >> 16);
}
__device__ __forceinline__ void gl_lds16(const void* g, const void* l) {
    __builtin_amdgcn_global_load_lds(
        (const __attribute__((address_space(1))) unsigned int*)(unsigned long long)g,
        (__attribute__((address_space(3))) unsigned int*)(unsigned long long)l,
        16, 0, 0);
}

// ============ bf16 MFMA GEMM ================================================
// REL=0: standard batch: Aoff=bz*Abat, Boff=bz*Bbat, Coff=bz*Cbat, bias+bz*bbat
// REL=1: bz = e*8+h (e=edge type 0..3, h=head 0..7):
//        Aoff=(e>>1)*Abat2 + h*N, Boff=bz*Bbat, Coff=e*Cbat2 + h*N, no bias.
// A row-major lda, Bt row-major [Npad x K] (=B^T), C bf16 row-major ldc.
// M fixed = MPAD (grid.y*128), K % 32 == 0, Bt has >= n0+128 rows per batch.
template<int REL>
__global__ __launch_bounds__(256) void mfma_gemm(
    const ushort_t* __restrict__ A, long Abat, long Abat2, int lda,
    const ushort_t* __restrict__ Bt, long Bbat,
    const float* __restrict__ bias, long bbat,
    ushort_t* __restrict__ C, long Cbat, long Cbat2, int ldc,
    int N, int K)
{
    __shared__ __align__(16) ushort_t As[128 * 32];
    __shared__ __align__(16) ushort_t Bs[128 * 32];
    const int t = threadIdx.x, lane = t & 63, w = t >> 6;
    const int quad = lane >> 4, l15 = lane & 15;
    const int m0 = blockIdx.y * 128, n0 = blockIdx.x * 128;
    const int bz = blockIdx.z;

    long Aoff, Coff;
    const float* bp = nullptr;
    if (REL) {
        const int e = bz >> 3, h = bz & 7;
        Aoff = (long)(e >> 1) * Abat2 + (long)h * N;
        Coff = (long)e * Cbat2 + (long)h * N;
    } else {
        Aoff = (long)bz * Abat;
        Coff = (long)bz * Cbat;
        if (bias) bp = bias + (long)bz * bbat;
    }
    const ushort_t* Ag = A + Aoff + (long)m0 * lda;
    const ushort_t* Bg = Bt + (long)bz * Bbat + (long)n0 * K;
    C += Coff;

    floatx4 acc[4][4];
    #pragma unroll
    for (int i = 0; i < 4; ++i)
        #pragma unroll
        for (int j = 0; j < 4; ++j)
            acc[i][j] = (floatx4){0.f, 0.f, 0.f, 0.f};

    const int wm = (w >> 1) * 64, wn = (w & 1) * 64;
    const int ar0 = t >> 2,         ak0 = (t & 3) * 8;
    const int ar1 = (256 + t) >> 2, ak1 = (t & 3) * 8;
    const char* lA0 = (const char*)As + (size_t)(w * 64) * 16;
    const char* lA1 = (const char*)As + (size_t)(256 + w * 64) * 16;
    const char* lB0 = (const char*)Bs + (size_t)(w * 64) * 16;
    const char* lB1 = (const char*)Bs + (size_t)(256 + w * 64) * 16;

    for (int k0 = 0; k0 < K; k0 += 32) {
        gl_lds16(Ag + (long)ar0 * lda + k0 + ak0, lA0);
        gl_lds16(Ag + (long)ar1 * lda + k0 + ak1, lA1);
        gl_lds16(Bg + (long)ar0 * K + k0 + ak0, lB0);
        gl_lds16(Bg + (long)ar1 * K + k0 + ak1, lB1);
        __syncthreads();
        bf16x8 a[4], b[4];
        #pragma unroll
        for (int mi = 0; mi < 4; ++mi)
            a[mi] = *(const bf16x8*)(As + (size_t)(wm + mi * 16 + l15) * 32 + quad * 8);
        #pragma unroll
        for (int ni = 0; ni < 4; ++ni)
            b[ni] = *(const bf16x8*)(Bs + (size_t)(wn + ni * 16 + l15) * 32 + quad * 8);
        #pragma unroll
        for (int mi = 0; mi < 4; ++mi)
            #pragma unroll
            for (int ni = 0; ni < 4; ++ni)
                acc[mi][ni] = __builtin_amdgcn_mfma_f32_16x16x32_bf16(
                    a[mi], b[ni], acc[mi][ni], 0, 0, 0);
        __syncthreads();
    }

    #pragma unroll
    for (int ni = 0; ni < 4; ++ni) {
        const int col = n0 + wn + ni * 16 + l15;
        if (col >= N) continue;
        const float bv = bp ? bp[col] : 0.f;
        #pragma unroll
        for (int mi = 0; mi < 4; ++mi) {
            const int row = m0 + wm + mi * 16 + quad * 4;
            #pragma unroll
            for (int r = 0; r < 4; ++r)
                C[(long)(row + r) * ldc + col] = f2bf(acc[mi][ni][r] + bv);
        }
    }
}

// ============ transpose + fp32->bf16 convert: out[Cpad x R] = in[R x C]^T ====
__global__ void transpose_conv_kernel(
    const float* __restrict__ in, long ibat, int R, int C,
    ushort_t* __restrict__ out, long obat, int Cpad)
{
    __shared__ float tile[32][33];
    in  += (long)blockIdx.z * ibat;
    out += (long)blockIdx.z * obat;
    const int r0 = blockIdx.x * 32, c0 = blockIdx.y * 32;
    const int tx = threadIdx.x, ty = threadIdx.y;
    #pragma unroll
    for (int i = 0; i < 4; ++i) {
        const int r = r0 + ty + i * 8, c = c0 + tx;
        tile[ty + i * 8][tx] = (r < R && c < C) ? in[(long)r * C + c] : 0.f;
    }
    __syncthreads();
    #pragma unroll
    for (int i = 0; i < 4; ++i) {
        const int oc = c0 + ty + i * 8, orr = r0 + tx;
        if (oc < Cpad && orr < R) out[(long)oc * R + orr] = f2bf(tile[tx][ty + i * 8]);
    }
}

// ============ pad-convert: fp32 [2][NN][F] -> bf16 [2][MPAD][F] ==============
__global__ void convpad_kernel(const float* __restrict__ in, ushort_t* __restrict__ out, int logF)
{
    const long per = (long)MPAD << logF;
    const long idx = (long)blockIdx.x * 256 + threadIdx.x;
    if (idx >= per) return;
    const int n = (int)(idx >> logF);
    const int c = (int)(idx & ((1 << logF) - 1));
    const int tt = blockIdx.y;
    float v = 0.f;
    if (n < NN) v = in[(((long)tt * NN + n) << logF) + c];
    out[(long)tt * per + idx] = f2bf(v);
}

__global__ void biascat_kernel(const float* __restrict__ b0, const float* __restrict__ b1,
                               const float* __restrict__ b2, float* __restrict__ out, int F)
{
    const int i = blockIdx.x * 256 + threadIdx.x;
    if (i >= 2 * 3 * F) return;
    const int tt = i / (3 * F), r = i % (3 * F);
    const int sec = r / F, c = r % F;
    const float* b = sec == 0 ? b0 : sec == 1 ? b1 : b2;
    out[i] = b[tt * F + c];
}

// ============ CSR build ======================================================
__global__ void izero_kernel(int* __restrict__ p, int n) {
    int i = blockIdx.x * 256 + threadIdx.x;
    if (i < n) p[i] = 0;
}

__global__ void hist_kernel(const int* __restrict__ e0, const int* __restrict__ e1,
                            const int* __restrict__ e2, const int* __restrict__ e3,
                            int* __restrict__ counts)
{
    const int i = blockIdx.x * 256 + threadIdx.x;
    if (i >= EE) return;
    const int ty = blockIdx.y;
    const int* ei = ty == 0 ? e0 : ty == 1 ? e1 : ty == 2 ? e2 : e3;
    atomicAdd(&counts[ty * NN + ei[EE + i]], 1);
}

__global__ __launch_bounds__(1024) void scan_kernel(
    const int* __restrict__ counts, int* __restrict__ rowptr, int* __restrict__ wofs)
{
    const int ty = blockIdx.x;
    const int t = threadIdx.x;
    __shared__ int sh[1024];
    __shared__ int carry;
    if (t == 0) carry = 0;
    __syncthreads();
    for (int base = 0; base < NN; base += 1024) {
        const int idx = base + t;
        const int v = (idx < NN) ? counts[ty * NN + idx] : 0;
        sh[t] = v;
        __syncthreads();
        for (int offs = 1; offs < 1024; offs <<= 1) {
            const int add = (t >= offs) ? sh[t - offs] : 0;
            __syncthreads();
            sh[t] += add;
            __syncthreads();
        }
        const int exc = carry + sh[t] - v;
        if (idx < NN) { rowptr[ty * (NN + 1) + idx] = exc; wofs[ty * NN + idx] = exc; }
        __syncthreads();
        if (t == 0) carry += sh[1023];
        __syncthreads();
    }
    if (t == 0) rowptr[ty * (NN + 1) + NN] = carry;
}

__global__ void scatter_kernel(const int* __restrict__ e0, const int* __restrict__ e1,
                               const int* __restrict__ e2, const int* __restrict__ e3,
                               int* __restrict__ wofs, int2* __restrict__ pairs)
{
    const int i = blockIdx.x * 256 + threadIdx.x;
    if (i >= EE) return;
    const int ty = blockIdx.y;
    const int* ei = ty == 0 ? e0 : ty == 1 ? e1 : ty == 2 ? e2 : e3;
    const int src = ei[i], dst = ei[EE + i];
    const int pos = atomicAdd(&wofs[ty * NN + dst], 1);
    pairs[(long)ty * EE + pos] = make_int2(i, src);
}

// ============ edge logits: one wave per edge, all 8 heads ====================
// NV = HD/512 (2 for HD=1024, 1 for HD=512). 8 lanes per head.
template<int NV>
__global__ __launch_bounds__(256) void edge_logits_kernel(
    const int* __restrict__ ei, const ushort_t* __restrict__ Qd, int ldq,
    const ushort_t* __restrict__ KR, const float* __restrict__ prel,
    float inv_sqrt_d, float* __restrict__ logit)
{
    const int wave = threadIdx.x >> 6, lane = threadIdx.x & 63;
    const int e = blockIdx.x * 4 + wave;
    if (e >= EE) return;
    const int src = ei[e], dst = ei[EE + e];
    const int HD = NV * 512;
    const ushort_t* q = Qd + (long)dst * ldq + lane * (NV * 8);
    const ushort_t* k = KR + (long)src * HD + lane * (NV * 8);
    float partial = 0.f;
    #pragma unroll
    for (int v = 0; v < NV; ++v) {
        const u16x8 q8 = *(const u16x8*)(q + v * 8);
        const u16x8 k8 = *(const u16x8*)(k + v * 8);
        #pragma unroll
        for (int j = 0; j < 8; ++j)
            partial = fmaf(bf2f(q8[j]), bf2f(k8[j]), partial);
    }
    partial += __shfl_xor(partial, 1);
    partial += __shfl_xor(partial, 2);
    partial += __shfl_xor(partial, 4);
    if ((lane & 7) == 0) {
        const int h = lane >> 3;
        logit[(long)e * 8 + h] = partial * prel[h] * inv_sqrt_d;
    }
}

// ============ per-dst softmax + aggregation (both edge types) + GELU + bf16 ==
// CPT = cols/thread: 4 for HD=1024, 2 for HD=512. One block per dst row.
template<int CPT>
__global__ __launch_bounds__(256) void agg_kernel(
    const int* __restrict__ rp0, const int2* __restrict__ pr0,
    const float* __restrict__ al0, const ushort_t* __restrict__ VR0,
    const int* __restrict__ rp1, const int2* __restrict__ pr1,
    const float* __restrict__ al1, const ushort_t* __restrict__ VR1,
    ushort_t* __restrict__ outp)
{
    const int HD = CPT * 256;
    const int dst = blockIdx.x;
    const int t = threadIdx.x;
    const int c0 = t * CPT;
    if (dst >= NN) {   // zero pad rows
        if (CPT == 4) *(u16x4*)(outp + (long)dst * HD + c0) = (u16x4){0, 0, 0, 0};
        else          *(u16x2*)(outp + (long)dst * HD + c0) = (u16x2){0, 0};
        return;
    }
    __shared__ float m_s[2][8], si_s[2][8];
    __shared__ int degs[2], starts[2];
    if (t < 2) {
        const int* rp = t ? rp1 : rp0;
        const int a = rp[dst], b = rp[dst + 1];
        starts[t] = a; degs[t] = b - a;
    }
    __syncthreads();
    if (t < 16) {
        const int ty = t >> 3, h = t & 7;
        const int2* pr = ty ? pr1 : pr0;
        const float* al = ty ? al1 : al0;
        const int s0 = starts[ty], dg = degs[ty];
        float m = -3.0e38f;
        for (int i = 0; i < dg; ++i)
            m = fmaxf(m, al[(long)pr[s0 + i].x * 8 + h]);
        float ssum = 0.f;
        for (int i = 0; i < dg; ++i)
            ssum += expf(al[(long)pr[s0 + i].x * 8 + h] - m);
        m_s[ty][h] = m;
        si_s[ty][h] = (dg > 0) ? 1.f / (ssum + 1e-16f) : 0.f;
    }
    __syncthreads();
    const int h = t >> 5;   // c0/D for both CPT cases
    float acc[CPT] = {};
    #pragma unroll
    for (int ty = 0; ty < 2; ++ty) {
        const int2* pr = ty ? pr1 : pr0;
        const float* al = ty ? al1 : al0;
        const ushort_t* VR = ty ? VR1 : VR0;
        const int s0 = starts[ty], dg = degs[ty];
        const float mm = m_s[ty][h], si = si_s[ty][h];
        for (int i = 0; i < dg; ++i) {
            const int2 p = pr[s0 + i];
            const float wgt = expf(al[(long)p.x * 8 + h] - mm) * si;
            const ushort_t* vrow = VR + (long)p.y * HD + c0;
            if (CPT == 4) {
                const u16x4 v = *(const u16x4*)vrow;
                #pragma unroll
                for (int j = 0; j < 4; ++j) acc[j] = fmaf(wgt, bf2f(v[j]), acc[j]);
            } else {
                const u16x2 v = *(const u16x2*)vrow;
                #pragma unroll
                for (int j = 0; j < 2; ++j) acc[j] = fmaf(wgt, bf2f(v[j]), acc[j]);
            }
        }
    }
    if (CPT == 4) {
        u16x4 o;
        #pragma unroll
        for (int j = 0; j < 4; ++j) o[j] = f2bf(gelu_f(acc[j]));
        *(u16x4*)(outp + (long)dst * HD + c0) = o;
    } else {
        u16x2 o;
        #pragma unroll
        for (int j = 0; j < 2; ++j) o[j] = f2bf(gelu_f(acc[j]));
        *(u16x2*)(outp + (long)dst * HD + c0) = o;
    }
}

// ============ final: logits = h2 @ Wlin + blin, row softmax ==================
__global__ __launch_bounds__(256) void final_kernel(
    const ushort_t* __restrict__ H2, const float* __restrict__ Wlin,
    const float* __restrict__ blin, float* __restrict__ outp)
{
    const int wave = threadIdx.x >> 6, lane = threadIdx.x & 63;
    const int node = blockIdx.x * 4 + wave;
    if (node >= 2 * NN) return;
    const int tt = (node >= NN) ? 1 : 0;
    const int n = node - tt * NN;
    const ushort_t* hrow = H2 + ((long)tt * MPAD + n) * 512;
    float acc[8] = {};
    for (int f = lane; f < 512; f += 64) {
        const float hv = bf2f(hrow[f]);
        const float* wr = Wlin + f * 8;
        #pragma unroll
        for (int o = 0; o < 8; ++o) acc[o] = fmaf(hv, wr[o], acc[o]);
    }
    #pragma unroll
    for (int o = 0; o < 8; ++o)
        #pragma unroll
        for (int off = 32; off > 0; off >>= 1)
            acc[o] += __shfl_xor(acc[o], off);
    if (lane == 0) {
        float mx = -3.0e38f;
        #pragma unroll
        for (int o = 0; o < 8; ++o) { acc[o] += blin[o]; mx = fmaxf(mx, acc[o]); }
        float ssum = 0.f;
        #pragma unroll
        for (int o = 0; o < 8; ++o) { acc[o] = expf(acc[o] - mx); ssum += acc[o]; }
        const float inv = 1.f / ssum;
        #pragma unroll
        for (int o = 0; o < 8; ++o) outp[(long)node * 8 + o] = acc[o] * inv;
    }
}

// =============================== host side ===================================
static void tconv_launch(const float* in, long ibat, int R, int C,
                         ushort_t* out, long obat, int Cpad, int batch, hipStream_t s)
{
    dim3 grid((R + 31) / 32, (Cpad + 31) / 32, batch);
    transpose_conv_kernel<<<grid, dim3(32, 8), 0, s>>>(in, ibat, R, C, out, obat, Cpad);
}

struct CsrBufs { int *rowptr, *pairs_dummy; int2* pairs; };

static void run_hgt_layer(
    const ushort_t* xb, int Fin, int F,      // F = Fout
    const ushort_t* wkqvT, const float* bkqv, const ushort_t* waT, const float* ba,
    const ushort_t* arelT, const ushort_t* mrelT, const float* prel,
    const int* const* ei, const int* rowptr, const int2* pairs,
    ushort_t* kqv, ushort_t* KRall, ushort_t* VRall, float* alpha,
    ushort_t* outg, ushort_t* hout, hipStream_t stream)
{
    const int D = F / NHEAD;
    const float inv_sqrt_d = 1.0f / sqrtf((float)D);
    const long NF = (long)MPAD * F;
    const int ldkqv = 3 * F;

    // fused K|Q|V projection: [2] x [MPAD x 3F] = xb @ [3F x Fin]^T
    {
        dim3 grid(3 * F / 128, MPAD / 128, 2);
        mfma_gemm<0><<<grid, 256, 0, stream>>>(
            xb, (long)MPAD * Fin, 0, Fin, wkqvT, (long)3 * F * Fin,
            bkqv, 3 * F, kqv, (long)MPAD * ldkqv, 0, ldkqv, 3 * F, Fin);
    }
    // relation transforms, all 4 types x 8 heads in one dispatch each
    {
        dim3 grid(1, MPAD / 128, 32);
        mfma_gemm<1><<<grid, 256, 0, stream>>>(          // KR from K section (col 0)
            kqv, 0, (long)MPAD * ldkqv, ldkqv, arelT, (long)128 * D,
            nullptr, 0, KRall, 0, NF, F, D, D);
        mfma_gemm<1><<<grid, 256, 0, stream>>>(          // VR from V section (col 2F)
            kqv + 2 * F, 0, (long)MPAD * ldkqv, ldkqv, mrelT, (long)128 * D,
            nullptr, 0, VRall, 0, NF, F, D, D);
    }
    // logits for each edge type (Q section at col F)
    for (int e = 0; e < 4; ++e) {
        const int dt = e & 1;
        if (F == 1024)
            edge_logits_kernel<2><<<(EE + 3) / 4, 256, 0, stream>>>(
                ei[e], kqv + (long)dt * MPAD * ldkqv + F, ldkqv,
                KRall + (long)e * NF, prel + e * 8, inv_sqrt_d, alpha + (long)e * EE * 8);
        else
            edge_logits_kernel<1><<<(EE + 3) / 4, 256, 0, stream>>>(
                ei[e], kqv + (long)dt * MPAD * ldkqv + F, ldkqv,
                KRall + (long)e * NF, prel + e * 8, inv_sqrt_d, alpha + (long)e * EE * 8);
    }
    // aggregation per dst type: dt=0 <- types {0,2}; dt=1 <- types {1,3}
    for (int dt = 0; dt < 2; ++dt) {
        const int e0 = dt, e1 = dt + 2;   // (0,2) or (1,3)
        if (F == 1024)
            agg_kernel<4><<<MPAD, 256, 0, stream>>>(
                rowptr + e0 * (NN + 1), pairs + (long)e0 * EE, alpha + (long)e0 * EE * 8, VRall + (long)e0 * NF,
                rowptr + e1 * (NN + 1), pairs + (long)e1 * EE, alpha + (long)e1 * EE * 8, VRall + (long)e1 * NF,
                outg + (long)dt * NF);
        else
            agg_kernel<2><<<MPAD, 256, 0, stream>>>(
                rowptr + e0 * (NN + 1), pairs + (long)e0 * EE, alpha + (long)e0 * EE * 8, VRall + (long)e0 * NF,
                rowptr + e1 * (NN + 1), pairs + (long)e1 * EE, alpha + (long)e1 * EE * 8, VRall + (long)e1 * NF,
                outg + (long)dt * NF);
    }
    // h = gelu(out) @ Wa + ba   (GELU already applied in agg)
    {
        dim3 grid(F / 128, MPAD / 128, 2);
        mfma_gemm<0><<<grid, 256, 0, stream>>>(
            outg, NF, 0, F, waT, (long)F * F, ba, F, hout, NF, 0, F, F, F);
    }
}

extern "C" void kernel_launch(void* const* d_in, const int* in_sizes, int n_in,
                              void* d_out, int out_size, void* d_ws, size_t ws_size,
                              hipStream_t stream)
{
    const float* x = (const float*)d_in[0];
    const int* ei_arr[4] = {(const int*)d_in[1], (const int*)d_in[2],
                            (const int*)d_in[3], (const int*)d_in[4]};
    const float* Wk1 = (const float*)d_in[5];   const float* bk1 = (const float*)d_in[6];
    const float* Wq1 = (const float*)d_in[7];   const float* bq1 = (const float*)d_in[8];
    const float* Wv1 = (const float*)d_in[9];   const float* bv1 = (const float*)d_in[10];
    const float* Wa1 = (const float*)d_in[11];  const float* ba1 = (const float*)d_in[12];
    const float* ar1 = (const float*)d_in[13];  const float* mr1 = (const float*)d_in[14];
    const float* pr1 = (const float*)d_in[15];
    const float* Wk2 = (const float*)d_in[16];  const float* bk2 = (const float*)d_in[17];
    const float* Wq2 = (const float*)d_in[18];  const float* bq2 = (const float*)d_in[19];
    const float* Wv2 = (const float*)d_in[20];  const float* bv2 = (const float*)d_in[21];
    const float* Wa2 = (const float*)d_in[22];  const float* ba2 = (const float*)d_in[23];
    const float* ar2 = (const float*)d_in[24];  const float* mr2 = (const float*)d_in[25];
    const float* pr2 = (const float*)d_in[26];
    const float* Wlin = (const float*)d_in[27]; const float* blin = (const float*)d_in[28];
    (void)in_sizes; (void)n_in; (void)out_size; (void)ws_size;

    // ---- workspace arena (~525 MB) ----
    char* base = (char*)d_ws;
    size_t off = 0;
    auto takeF = [&](size_t n) { float* p = (float*)(base + off); off += n * 4; return p; };
    auto takeU = [&](size_t n) { ushort_t* p = (ushort_t*)(base + off);
                                 off += n * 2; off = (off + 15) & ~(size_t)15; return p; };
    auto takeI = [&](size_t n) { int* p = (int*)(base + off); off += n * 4; return p; };

    float* alpha = takeF((size_t)4 * EE * 8);
    float* bkqv1 = takeF((size_t)2 * 3072);
    float* bkqv2 = takeF((size_t)2 * 1536);

    ushort_t* xb     = takeU((size_t)2 * MPAD * 2048);
    ushort_t* kqv    = takeU((size_t)2 * MPAD * 3072);
    ushort_t* KRall  = takeU((size_t)4 * MPAD * 1024);
    ushort_t* VRall  = takeU((size_t)4 * MPAD * 1024);
    ushort_t* outg   = takeU((size_t)2 * MPAD * 1024);
    ushort_t* h1b    = takeU((size_t)2 * MPAD * 1024);
    ushort_t* h2b    = takeU((size_t)2 * MPAD * 512);
    ushort_t* wkqv1t = takeU((size_t)2 * 3072 * 2048);
    ushort_t* wat1   = takeU((size_t)2 * 1024 * 1024);
    ushort_t* wkqv2t = takeU((size_t)2 * 1536 * 1024);
    ushort_t* wat2   = takeU((size_t)2 * 512 * 512);
    ushort_t* ar1t   = takeU((size_t)32 * 128 * 128);
    ushort_t* mr1t   = takeU((size_t)32 * 128 * 128);
    ushort_t* ar2t   = takeU((size_t)32 * 128 * 64);
    ushort_t* mr2t   = takeU((size_t)32 * 128 * 64);

    int*  counts = takeI((size_t)4 * NN);
    int*  wofs   = takeI((size_t)4 * NN);
    int*  rowptr = takeI((size_t)4 * (NN + 1));
    int2* pairs  = (int2*)takeI((size_t)4 * EE * 2);

    // ---- input conversions ----
    {
        const long per = (long)MPAD << 11;
        dim3 grid((unsigned)((per + 255) / 256), 2);
        convpad_kernel<<<grid, 256, 0, stream>>>(x, xb, 11);
    }
    // weights: stacked K|Q|V transposed per type
    tconv_launch(Wk1, (long)2048 * 1024, 2048, 1024, wkqv1t,                  (long)3072 * 2048, 1024, 2, stream);
    tconv_launch(Wq1, (long)2048 * 1024, 2048, 1024, wkqv1t + (long)1024 * 2048, (long)3072 * 2048, 1024, 2, stream);
    tconv_launch(Wv1, (long)2048 * 1024, 2048, 1024, wkqv1t + (long)2048 * 2048, (long)3072 * 2048, 1024, 2, stream);
    tconv_launch(Wa1, (long)1024 * 1024, 1024, 1024, wat1, (long)1024 * 1024, 1024, 2, stream);
    tconv_launch(Wk2, (long)1024 * 512, 1024, 512, wkqv2t,                   (long)1536 * 1024, 512, 2, stream);
    tconv_launch(Wq2, (long)1024 * 512, 1024, 512, wkqv2t + (long)512 * 1024,  (long)1536 * 1024, 512, 2, stream);
    tconv_launch(Wv2, (long)1024 * 512, 1024, 512, wkqv2t + (long)1024 * 1024, (long)1536 * 1024, 512, 2, stream);
    tconv_launch(Wa2, (long)512 * 512, 512, 512, wat2, (long)512 * 512, 512, 2, stream);
    tconv_launch(ar1, (long)128 * 128, 128, 128, ar1t, (long)128 * 128, 128, 32, stream);
    tconv_launch(mr1, (long)128 * 128, 128, 128, mr1t, (long)128 * 128, 128, 32, stream);
    tconv_launch(ar2, (long)64 * 64, 64, 64, ar2t, (long)128 * 64, 128, 32, stream);
    tconv_launch(mr2, (long)64 * 64, 64, 64, mr2t, (long)128 * 64, 128, 32, stream);
    biascat_kernel<<<(2 * 3072 + 255) / 256, 256, 0, stream>>>(bk1, bq1, bv1, bkqv1, 1024);
    biascat_kernel<<<(2 * 1536 + 255) / 256, 256, 0, stream>>>(bk2, bq2, bv2, bkqv2, 512);

    // ---- CSR build (edges identical for both layers) ----
    izero_kernel<<<(4 * NN + 255) / 256, 256, 0, stream>>>(counts, 4 * NN);
    {
        dim3 grid((EE + 255) / 256, 4);
        hist_kernel<<<grid, 256, 0, stream>>>(ei_arr[0], ei_arr[1], ei_arr[2], ei_arr[3], counts);
        scan_kernel<<<4, 1024, 0, stream>>>(counts, rowptr, wofs);
        scatter_kernel<<<grid, 256, 0, stream>>>(ei_arr[0], ei_arr[1], ei_arr[2], ei_arr[3], wofs, pairs);
    }

    // Layer 1: 2048 -> 1024 (D=128)
    run_hgt_layer(xb, 2048, 1024, wkqv1t, bkqv1, wat1, ba1, ar1t, mr1t, pr1,
                  ei_arr, rowptr, pairs, kqv, KRall, VRall, alpha, outg, h1b, stream);
    // Layer 2: 1024 -> 512 (D=64), reuses buffers
    run_hgt_layer(h1b, 1024, 512, wkqv2t, bkqv2, wat2, ba2, ar2t, mr2t, pr2,
                  ei_arr, rowptr, pairs, kqv, KRall, VRall, alpha, outg, h2b, stream);

    final_kernel<<<(2 * NN + 3) / 4, 256, 0, stream>>>(h2b, Wlin, blin, (float*)d_out);
}